// Round 7
// baseline (166.417 us; speedup 1.0000x reference)
//
#include <hip/hip_runtime.h>

#define NAG 16
#define SPB 4        // scenes per block = 2 iterations x 2 scenes (BN=2)
#define NBLK 2048    // 2048 * 4 = 8192 scenes
#define R2f 64.0f

typedef unsigned short u16;
typedef __attribute__((ext_vector_type(8))) short short8;
typedef __attribute__((ext_vector_type(4))) float f32x4;

#define MFMA(a, b, c) __builtin_amdgcn_mfma_f32_16x16x32_bf16(a, b, c, 0, 0, 0)

// ws blob offsets in u16 units (R3-proven layout)
#define OFF_B1 0        // [Wroot1;Wrel1]  K=128 N=128  S=4 T=8
#define OFF_B2 16384    // [Wroot2;Wrel2]  K=256 N=128  S=8 T=8
#define OFF_H1 49152    // Wh1             K=256 N=64   S=8 T=4
#define OFF_H2 65536    // Wh2             K=64  N=32   S=2 T=2
#define OFF_H3 67584    // Wh3             K=32  N=16   S=1 T=1
#define SWZ_UNITS 8512

__device__ __forceinline__ u16 f2b(float f) {
    unsigned u = __float_as_uint(f);
    unsigned r = u + 0x7FFFu + ((u >> 16) & 1u);   // RNE
    return (u16)(r >> 16);
}

// ---------------- weight pre-swizzle: W[K][N] f32 -> fragment order bf16 -----
// unit u = (s, t, lane); element j: k = s*32 + (lane>>4)*8 + j, n = t*16 + (lane&15)
__global__ __launch_bounds__(256) void swizzle_w(
    const float* __restrict__ Wrel1, const float* __restrict__ Wroot1,
    const float* __restrict__ Wrel2, const float* __restrict__ Wroot2,
    const float* __restrict__ Wh1,  const float* __restrict__ Wh2,
    const float* __restrict__ Wh3,  u16* __restrict__ ws)
{
    const int u = blockIdx.x * 256 + threadIdx.x;
    if (u >= SWZ_UNITS) return;

    int v, T, N, ksplit;
    const float *W, *W2;
    u16* dst;
    if (u < 2048)      { v = u;        T = 8; N = 128; ksplit = 64;  W = Wroot1; W2 = Wrel1; dst = ws + OFF_B1 + v * 8; }
    else if (u < 6144) { v = u - 2048; T = 8; N = 128; ksplit = 128; W = Wroot2; W2 = Wrel2; dst = ws + OFF_B2 + v * 8; }
    else if (u < 8192) { v = u - 6144; T = 4; N = 64;  ksplit = 1 << 30; W = Wh1; W2 = Wh1; dst = ws + OFF_H1 + v * 8; }
    else if (u < 8448) { v = u - 8192; T = 2; N = 32;  ksplit = 1 << 30; W = Wh2; W2 = Wh2; dst = ws + OFF_H2 + v * 8; }
    else               { v = u - 8448; T = 1; N = 16;  ksplit = 1 << 30; W = Wh3; W2 = Wh3; dst = ws + OFF_H3 + v * 8; }

    const int lane = v & 63;
    const int t = (v >> 6) % T;
    const int s = (v >> 6) / T;
    const int n = t * 16 + (lane & 15);
    const int k0 = s * 32 + (lane >> 4) * 8;
    #pragma unroll
    for (int j = 0; j < 8; ++j) {
        const int k = k0 + j;
        const float val = (k < ksplit) ? W[k * N + n] : W2[(k - ksplit) * N + n];
        dst[j] = f2b(val);
    }
}

// one 16B load per fragment; A-frag of W^T == B-frag of W (same (k,n) mapping)
__device__ __forceinline__ short8 ldfrag(const u16* __restrict__ ws, int off,
                                         int T, int s, int tile, int lane) {
    return *(const short8*)(ws + off + (size_t)(((s * T + tile) * 64 + lane) * 8));
}

// adjacency B-fragment: B[k=agent j][n=agent i]; adj symmetric; k>=16 -> 0
__device__ __forceinline__ short8 make_adjB(unsigned m, int q) {
    union { short8 v; unsigned u[4]; } r;
    #pragma unroll
    for (int jj = 0; jj < 4; ++jj) {
        const int k0 = q * 8 + 2 * jj;
        const unsigned lo = ((m >> k0) & 1u) ? 0x3F80u : 0u;        // bf16 1.0
        const unsigned hi = ((m >> (k0 + 1)) & 1u) ? 0x3F80u : 0u;
        r.u[jj] = lo | (hi << 16);
    }
    return r.v;
}

__device__ __forceinline__ void relu_store4(u16* d, f32x4 a) {
    const unsigned p0 = (unsigned)f2b(fmaxf(a[0], 0.f)) | ((unsigned)f2b(fmaxf(a[1], 0.f)) << 16);
    const unsigned p1 = (unsigned)f2b(fmaxf(a[2], 0.f)) | ((unsigned)f2b(fmaxf(a[3], 0.f)) << 16);
    uint2 u; u.x = p0; u.y = p1;
    *(uint2*)d = u;
}

__global__ __launch_bounds__(256) void gnn_fused3(
    const float* __restrict__ x, const float* __restrict__ pos,
    const float* __restrict__ brel1, const float* __restrict__ brel2,
    const float* __restrict__ bh1,  const float* __restrict__ bh2,
    const float* __restrict__ bh3,
    const u16* __restrict__ ws, float* __restrict__ out)
{
    // slot-indexed (BN=2). strides keep 16B alignment for b128 reads.
    __shared__ __align__(16) u16 xb[2][16 * 72];
    __shared__ __align__(16) u16 yT[2][128 * 40];   // [ch][agent0..15 | 16..31 zero]
    __shared__ __align__(16) u16 x1b[2][16 * 136];
    __shared__ __align__(16) u16 x2b[2][16 * 136];
    __shared__ __align__(16) u16 h1b[2][16 * 72];
    __shared__ __align__(16) u16 h2b[2][16 * 40];
    __shared__ unsigned mask[2][NAG];

    const int t = threadIdx.x;
    const int wv = t >> 6, lane = t & 63, mrow = lane & 15, q = lane >> 4;
    const int t0 = 2 * wv, t1 = 2 * wv + 1;

    // zero yT agent-pad (cols 16..31) once; never overwritten
    for (int i = t; i < 2 * 128 * 16; i += 256) {
        const int slot = i >> 11, rem = i & 2047;
        yT[slot][(rem >> 4) * 40 + 16 + (rem & 15)] = 0;
    }

    const float4 br1a = *(const float4*)(brel1 + t0 * 16 + q * 4);
    const float4 br1b = *(const float4*)(brel1 + t1 * 16 + q * 4);
    const float4 br2a = *(const float4*)(brel2 + t0 * 16 + q * 4);
    const float4 br2b = *(const float4*)(brel2 + t1 * 16 + q * 4);
    const float4 bb1  = *(const float4*)(bh1 + wv * 16 + q * 4);
    const float4 bb2  = *(const float4*)(bh2 + (wv & 1) * 16 + q * 4);
    const float4 bb3  = *(const float4*)(bh3 + q * 4);

    #pragma unroll 1
    for (int g = 0; g < SPB / 2; ++g) {
        const size_t sA = (size_t)blockIdx.x * SPB + 2 * g;

        // ---- S0: stage x for both scenes + adjacency masks ----
        {
            const int i0 = t * 4;
            #pragma unroll
            for (int sl = 0; sl < 2; ++sl) {
                const float4 v = *(const float4*)(x + (sA + sl) * (NAG * 64) + i0);
                const unsigned p0 = (unsigned)f2b(v.x) | ((unsigned)f2b(v.y) << 16);
                const unsigned p1 = (unsigned)f2b(v.z) | ((unsigned)f2b(v.w) << 16);
                uint2 u; u.x = p0; u.y = p1;
                *(uint2*)&xb[sl][(i0 >> 6) * 72 + (i0 & 63)] = u;
            }
        }
        if (t < 32) {
            const int sl = t >> 4, a = t & 15;
            const float* pp = pos + (sA + sl) * (NAG * 2);
            const float ax = pp[2 * a], ay = pp[2 * a + 1];
            unsigned m = 0;
            for (int j = 0; j < NAG; ++j) {
                const float dx = ax - pp[2 * j], dy = ay - pp[2 * j + 1];
                if (dx * dx + dy * dy <= R2f && j != a) m |= (1u << j);
            }
            mask[sl][a] = m;
        }
        __syncthreads();

        const short8 adjA = make_adjB(mask[0][mrow], q);
        const short8 adjBv = make_adjB(mask[1][mrow], q);

        // ---- S1: y^T = Wrel1^T @ x, both scenes -> yT ----
        {
            f32x4 aA0 = {0.f,0.f,0.f,0.f}, aA1 = aA0, aB0 = aA0, aB1 = aA0;
            #pragma unroll
            for (int s = 0; s < 2; ++s) {
                const short8 w0 = ldfrag(ws, OFF_B1, 8, s + 2, t0, lane);   // Wrel1
                const short8 w1 = ldfrag(ws, OFF_B1, 8, s + 2, t1, lane);
                const short8 bA = *(const short8*)&xb[0][mrow * 72 + s * 32 + q * 8];
                const short8 bB = *(const short8*)&xb[1][mrow * 72 + s * 32 + q * 8];
                aA0 = MFMA(w0, bA, aA0); aA1 = MFMA(w1, bA, aA1);
                aB0 = MFMA(w0, bB, aB0); aB1 = MFMA(w1, bB, aB1);
            }
            #pragma unroll
            for (int r = 0; r < 4; ++r) {
                yT[0][(t0 * 16 + q * 4 + r) * 40 + mrow] = f2b(aA0[r]);
                yT[0][(t1 * 16 + q * 4 + r) * 40 + mrow] = f2b(aA1[r]);
                yT[1][(t0 * 16 + q * 4 + r) * 40 + mrow] = f2b(aB0[r]);
                yT[1][(t1 * 16 + q * 4 + r) * 40 + mrow] = f2b(aB1[r]);
            }
        }
        __syncthreads();

        // ---- S2: x1 = relu(y^T@adj + Wroot1^T@x + b1) -> x1b ----
        {
            f32x4 aA0 = {br1a.x, br1a.y, br1a.z, br1a.w};
            f32x4 aA1 = {br1b.x, br1b.y, br1b.z, br1b.w};
            f32x4 aB0 = aA0, aB1 = aA1;
            const short8 yA0 = *(const short8*)&yT[0][(t0 * 16 + mrow) * 40 + q * 8];
            const short8 yA1 = *(const short8*)&yT[0][(t1 * 16 + mrow) * 40 + q * 8];
            const short8 yB0 = *(const short8*)&yT[1][(t0 * 16 + mrow) * 40 + q * 8];
            const short8 yB1 = *(const short8*)&yT[1][(t1 * 16 + mrow) * 40 + q * 8];
            aA0 = MFMA(yA0, adjA, aA0);  aA1 = MFMA(yA1, adjA, aA1);
            aB0 = MFMA(yB0, adjBv, aB0); aB1 = MFMA(yB1, adjBv, aB1);
            #pragma unroll
            for (int s = 0; s < 2; ++s) {
                const short8 w0 = ldfrag(ws, OFF_B1, 8, s, t0, lane);       // Wroot1
                const short8 w1 = ldfrag(ws, OFF_B1, 8, s, t1, lane);
                const short8 bA = *(const short8*)&xb[0][mrow * 72 + s * 32 + q * 8];
                const short8 bB = *(const short8*)&xb[1][mrow * 72 + s * 32 + q * 8];
                aA0 = MFMA(w0, bA, aA0); aA1 = MFMA(w1, bA, aA1);
                aB0 = MFMA(w0, bB, aB0); aB1 = MFMA(w1, bB, aB1);
            }
            relu_store4(&x1b[0][mrow * 136 + t0 * 16 + q * 4], aA0);
            relu_store4(&x1b[0][mrow * 136 + t1 * 16 + q * 4], aA1);
            relu_store4(&x1b[1][mrow * 136 + t0 * 16 + q * 4], aB0);
            relu_store4(&x1b[1][mrow * 136 + t1 * 16 + q * 4], aB1);
        }
        __syncthreads();

        // ---- S3: y^T = Wrel2^T @ x1 -> yT ----
        {
            f32x4 aA0 = {0.f,0.f,0.f,0.f}, aA1 = aA0, aB0 = aA0, aB1 = aA0;
            #pragma unroll
            for (int s = 0; s < 4; ++s) {
                const short8 w0 = ldfrag(ws, OFF_B2, 8, s + 4, t0, lane);   // Wrel2
                const short8 w1 = ldfrag(ws, OFF_B2, 8, s + 4, t1, lane);
                const short8 bA = *(const short8*)&x1b[0][mrow * 136 + s * 32 + q * 8];
                const short8 bB = *(const short8*)&x1b[1][mrow * 136 + s * 32 + q * 8];
                aA0 = MFMA(w0, bA, aA0); aA1 = MFMA(w1, bA, aA1);
                aB0 = MFMA(w0, bB, aB0); aB1 = MFMA(w1, bB, aB1);
            }
            #pragma unroll
            for (int r = 0; r < 4; ++r) {
                yT[0][(t0 * 16 + q * 4 + r) * 40 + mrow] = f2b(aA0[r]);
                yT[0][(t1 * 16 + q * 4 + r) * 40 + mrow] = f2b(aA1[r]);
                yT[1][(t0 * 16 + q * 4 + r) * 40 + mrow] = f2b(aB0[r]);
                yT[1][(t1 * 16 + q * 4 + r) * 40 + mrow] = f2b(aB1[r]);
            }
        }
        __syncthreads();

        // ---- S4: x2 = relu(y^T@adj + Wroot2^T@x1 + b2) -> x2b ----
        {
            f32x4 aA0 = {br2a.x, br2a.y, br2a.z, br2a.w};
            f32x4 aA1 = {br2b.x, br2b.y, br2b.z, br2b.w};
            f32x4 aB0 = aA0, aB1 = aA1;
            const short8 yA0 = *(const short8*)&yT[0][(t0 * 16 + mrow) * 40 + q * 8];
            const short8 yA1 = *(const short8*)&yT[0][(t1 * 16 + mrow) * 40 + q * 8];
            const short8 yB0 = *(const short8*)&yT[1][(t0 * 16 + mrow) * 40 + q * 8];
            const short8 yB1 = *(const short8*)&yT[1][(t1 * 16 + mrow) * 40 + q * 8];
            aA0 = MFMA(yA0, adjA, aA0);  aA1 = MFMA(yA1, adjA, aA1);
            aB0 = MFMA(yB0, adjBv, aB0); aB1 = MFMA(yB1, adjBv, aB1);
            #pragma unroll
            for (int s = 0; s < 4; ++s) {
                const short8 w0 = ldfrag(ws, OFF_B2, 8, s, t0, lane);       // Wroot2
                const short8 w1 = ldfrag(ws, OFF_B2, 8, s, t1, lane);
                const short8 bA = *(const short8*)&x1b[0][mrow * 136 + s * 32 + q * 8];
                const short8 bB = *(const short8*)&x1b[1][mrow * 136 + s * 32 + q * 8];
                aA0 = MFMA(w0, bA, aA0); aA1 = MFMA(w1, bA, aA1);
                aB0 = MFMA(w0, bB, aB0); aB1 = MFMA(w1, bB, aB1);
            }
            relu_store4(&x2b[0][mrow * 136 + t0 * 16 + q * 4], aA0);
            relu_store4(&x2b[0][mrow * 136 + t1 * 16 + q * 4], aA1);
            relu_store4(&x2b[1][mrow * 136 + t0 * 16 + q * 4], aB0);
            relu_store4(&x2b[1][mrow * 136 + t1 * 16 + q * 4], aB1);
        }
        __syncthreads();

        // ---- S5: h1 = relu(Wh1^T @ [x1|x2] + bh1), tile = wv, both scenes ----
        {
            f32x4 aA = {bb1.x, bb1.y, bb1.z, bb1.w};
            f32x4 aB = aA;
            #pragma unroll
            for (int s = 0; s < 8; ++s) {
                const short8 w = ldfrag(ws, OFF_H1, 4, s, wv, lane);
                const short8 bA = (s < 4)
                    ? *(const short8*)&x1b[0][mrow * 136 + s * 32 + q * 8]
                    : *(const short8*)&x2b[0][mrow * 136 + (s - 4) * 32 + q * 8];
                const short8 bB = (s < 4)
                    ? *(const short8*)&x1b[1][mrow * 136 + s * 32 + q * 8]
                    : *(const short8*)&x2b[1][mrow * 136 + (s - 4) * 32 + q * 8];
                aA = MFMA(w, bA, aA);
                aB = MFMA(w, bB, aB);
            }
            relu_store4(&h1b[0][mrow * 72 + wv * 16 + q * 4], aA);
            relu_store4(&h1b[1][mrow * 72 + wv * 16 + q * 4], aB);
        }
        __syncthreads();

        // ---- S6: h2 = relu(Wh2^T @ h1 + bh2); waves 0,1 -> scene A, 2,3 -> B ----
        {
            const int slot = wv >> 1, tile = wv & 1;
            f32x4 a = {bb2.x, bb2.y, bb2.z, bb2.w};
            #pragma unroll
            for (int s = 0; s < 2; ++s) {
                const short8 w = ldfrag(ws, OFF_H2, 2, s, tile, lane);
                const short8 b = *(const short8*)&h1b[slot][mrow * 72 + s * 32 + q * 8];
                a = MFMA(w, b, a);
            }
            relu_store4(&h2b[slot][mrow * 40 + tile * 16 + q * 4], a);
        }
        __syncthreads();

        // ---- S7: out = Wh3^T @ h2 + bh3; wave 0 -> scene A, wave 1 -> scene B ----
        if (wv < 2) {
            f32x4 a = {bb3.x, bb3.y, bb3.z, bb3.w};
            const short8 w = ldfrag(ws, OFF_H3, 1, 0, 0, lane);
            const short8 b = *(const short8*)&h2b[wv][mrow * 40 + q * 8];
            a = MFMA(w, b, a);
            float4 o; o.x = a[0]; o.y = a[1]; o.z = a[2]; o.w = a[3];
            *(float4*)(out + (sA + wv) * (NAG * 16) + mrow * 16 + q * 4) = o;
        }
        // no barrier: next S0's writes (xb, mask) race only with reads >=2 barriers old
    }
}

extern "C" void kernel_launch(void* const* d_in, const int* in_sizes, int n_in,
                              void* d_out, int out_size, void* d_ws, size_t ws_size,
                              hipStream_t stream) {
    const float* x      = (const float*)d_in[0];
    const float* pos    = (const float*)d_in[1];
    const float* Wrel1  = (const float*)d_in[2];
    const float* brel1  = (const float*)d_in[3];
    const float* Wroot1 = (const float*)d_in[4];
    const float* Wrel2  = (const float*)d_in[5];
    const float* brel2  = (const float*)d_in[6];
    const float* Wroot2 = (const float*)d_in[7];
    const float* Wh1    = (const float*)d_in[8];
    const float* bh1    = (const float*)d_in[9];
    const float* Wh2    = (const float*)d_in[10];
    const float* bh2    = (const float*)d_in[11];
    const float* Wh3    = (const float*)d_in[12];
    const float* bh3    = (const float*)d_in[13];
    u16* ws = (u16*)d_ws;

    swizzle_w<<<(SWZ_UNITS + 255) / 256, 256, 0, stream>>>(
        Wrel1, Wroot1, Wrel2, Wroot2, Wh1, Wh2, Wh3, ws);
    gnn_fused3<<<NBLK, 256, 0, stream>>>(
        x, pos, brel1, brel2, bh1, bh2, bh3, ws, (float*)d_out);
}

// Round 8
// 135.569 us; speedup vs baseline: 1.2275x; 1.2275x over previous
//
#include <hip/hip_runtime.h>

#define NAG 16
#define SPB 4        // scenes per block, processed as one M=64 batch
#define NBLK 2048    // 2048 * 4 = 8192 scenes, single pass per block
#define R2f 64.0f

typedef unsigned short u16;
typedef __attribute__((ext_vector_type(8))) short short8;
typedef __attribute__((ext_vector_type(4))) float f32x4;

#define MFMA(a, b, c) __builtin_amdgcn_mfma_f32_16x16x32_bf16(a, b, c, 0, 0, 0)

// ws blob offsets in u16 units (R3-proven layout)
#define OFF_B1 0        // [Wroot1;Wrel1]  K=128 N=128  S=4 T=8
#define OFF_B2 16384    // [Wroot2;Wrel2]  K=256 N=128  S=8 T=8
#define OFF_H1 49152    // Wh1             K=256 N=64   S=8 T=4
#define OFF_H2 65536    // Wh2             K=64  N=32   S=2 T=2
#define OFF_H3 67584    // Wh3             K=32  N=16   S=1 T=1
#define SWZ_UNITS 8512

__device__ __forceinline__ u16 f2b(float f) {
    unsigned u = __float_as_uint(f);
    unsigned r = u + 0x7FFFu + ((u >> 16) & 1u);   // RNE
    return (u16)(r >> 16);
}

// ---------------- weight pre-swizzle: W[K][N] f32 -> fragment order bf16 -----
__global__ __launch_bounds__(256) void swizzle_w(
    const float* __restrict__ Wrel1, const float* __restrict__ Wroot1,
    const float* __restrict__ Wrel2, const float* __restrict__ Wroot2,
    const float* __restrict__ Wh1,  const float* __restrict__ Wh2,
    const float* __restrict__ Wh3,  u16* __restrict__ ws)
{
    const int u = blockIdx.x * 256 + threadIdx.x;
    if (u >= SWZ_UNITS) return;

    int v, T, N, ksplit;
    const float *W, *W2;
    u16* dst;
    if (u < 2048)      { v = u;        T = 8; N = 128; ksplit = 64;  W = Wroot1; W2 = Wrel1; dst = ws + OFF_B1 + v * 8; }
    else if (u < 6144) { v = u - 2048; T = 8; N = 128; ksplit = 128; W = Wroot2; W2 = Wrel2; dst = ws + OFF_B2 + v * 8; }
    else if (u < 8192) { v = u - 6144; T = 4; N = 64;  ksplit = 1 << 30; W = Wh1; W2 = Wh1; dst = ws + OFF_H1 + v * 8; }
    else if (u < 8448) { v = u - 8192; T = 2; N = 32;  ksplit = 1 << 30; W = Wh2; W2 = Wh2; dst = ws + OFF_H2 + v * 8; }
    else               { v = u - 8448; T = 1; N = 16;  ksplit = 1 << 30; W = Wh3; W2 = Wh3; dst = ws + OFF_H3 + v * 8; }

    const int lane = v & 63;
    const int t = (v >> 6) % T;
    const int s = (v >> 6) / T;
    const int n = t * 16 + (lane & 15);
    const int k0 = s * 32 + (lane >> 4) * 8;
    #pragma unroll
    for (int j = 0; j < 8; ++j) {
        const int k = k0 + j;
        const float val = (k < ksplit) ? W[k * N + n] : W2[(k - ksplit) * N + n];
        dst[j] = f2b(val);
    }
}

__device__ __forceinline__ short8 ldfrag(const u16* __restrict__ ws, int off,
                                         int T, int s, int tile, int lane) {
    return *(const short8*)(ws + off + (size_t)(((s * T + tile) * 64 + lane) * 8));
}

// adjacency A-fragment for scene g paired in a 32-row K window (2 scenes):
// A[m=lane&15][k=q*8+j] = adj bit, valid only in the half this scene occupies.
__device__ __forceinline__ short8 make_adjA(unsigned m, int q, int odd) {
    union { short8 v; unsigned u[4]; } r;
    const bool on = (q >> 1) == odd;
    const int base = (q & 1) * 8;
    #pragma unroll
    for (int jj = 0; jj < 4; ++jj) {
        const int k0 = base + 2 * jj;
        const unsigned lo = (on && ((m >> k0) & 1u)) ? 0x3F80u : 0u;       // bf16 1.0
        const unsigned hi = (on && ((m >> (k0 + 1)) & 1u)) ? 0x3F80u : 0u;
        r.u[jj] = lo | (hi << 16);
    }
    return r.v;
}

__device__ __forceinline__ void relu_store4(u16* d, f32x4 a) {
    const unsigned p0 = (unsigned)f2b(fmaxf(a[0], 0.f)) | ((unsigned)f2b(fmaxf(a[1], 0.f)) << 16);
    const unsigned p1 = (unsigned)f2b(fmaxf(a[2], 0.f)) | ((unsigned)f2b(fmaxf(a[3], 0.f)) << 16);
    uint2 u; u.x = p0; u.y = p1;
    *(uint2*)d = u;
}

// LDS pool offsets (u16 units), all 16B-aligned; aliased regions noted.
// XCAT  [64][136]  rows=scene agents, cols 0..63 x, 64..127 agg1   (8704)
// XT    [64][72]   x^T: rows=ch, cols=row 0..63 (+pad)             (4608)
// XCAT2 [64][264]  cols 0..127 x1, 128..255 agg2                   (16896)
// X1T   [128][72]  x1^T                                            (9216)
// X2  aliases XCAT (dead after GEMM1);  H1 aliases XT (dead after agg1);
// H2 [64][40] aliases X1T (dead after agg2).  Total 39424 u16 = 78.8 KB.
__global__ __launch_bounds__(256) void gnn_fused4(
    const float* __restrict__ x, const float* __restrict__ pos,
    const float* __restrict__ brel1, const float* __restrict__ brel2,
    const float* __restrict__ bh1,  const float* __restrict__ bh2,
    const float* __restrict__ bh3,
    const u16* __restrict__ ws, float* __restrict__ out)
{
    __shared__ __align__(16) u16 pool[39424];
    __shared__ unsigned mask[64];
    u16* const xcat = pool;           // [64][136]
    u16* const xT   = pool + 8704;    // [64][72]
    u16* const xc2  = pool + 13312;   // [64][264]
    u16* const x1T  = pool + 30208;   // [128][72]
    u16* const x2b  = pool;           // alias XCAT
    u16* const h1b  = pool + 8704;    // alias XT
    u16* const h2b  = pool + 30208;   // alias X1T, [64][40]

    const int t = threadIdx.x;
    const int wv = t >> 6, lane = t & 63, ln = lane & 15, q = lane >> 4;
    const size_t sA = (size_t)blockIdx.x * SPB;

    // ---- S0: stage x -> xcat cols 0..63 (bf16) + xT; adjacency masks ----
    {
        const int r = t >> 2;                 // 0..63 row
        const int co = (t & 3) * 16;          // channel offset
        const float* src = x + (sA * 16 + r) * 64 + co;
        const float4 v0 = *(const float4*)(src);
        const float4 v1 = *(const float4*)(src + 4);
        const float4 v2 = *(const float4*)(src + 8);
        const float4 v3 = *(const float4*)(src + 12);
        u16 h[16];
        h[0] = f2b(v0.x); h[1] = f2b(v0.y); h[2]  = f2b(v0.z); h[3]  = f2b(v0.w);
        h[4] = f2b(v1.x); h[5] = f2b(v1.y); h[6]  = f2b(v1.z); h[7]  = f2b(v1.w);
        h[8] = f2b(v2.x); h[9] = f2b(v2.y); h[10] = f2b(v2.z); h[11] = f2b(v2.w);
        h[12]= f2b(v3.x); h[13]= f2b(v3.y); h[14] = f2b(v3.z); h[15] = f2b(v3.w);
        uint4 ua, ub;
        ua.x = (unsigned)h[0]  | ((unsigned)h[1]  << 16);
        ua.y = (unsigned)h[2]  | ((unsigned)h[3]  << 16);
        ua.z = (unsigned)h[4]  | ((unsigned)h[5]  << 16);
        ua.w = (unsigned)h[6]  | ((unsigned)h[7]  << 16);
        ub.x = (unsigned)h[8]  | ((unsigned)h[9]  << 16);
        ub.y = (unsigned)h[10] | ((unsigned)h[11] << 16);
        ub.z = (unsigned)h[12] | ((unsigned)h[13] << 16);
        ub.w = (unsigned)h[14] | ((unsigned)h[15] << 16);
        *(uint4*)&xcat[r * 136 + co]     = ua;
        *(uint4*)&xcat[r * 136 + co + 8] = ub;
        #pragma unroll
        for (int i = 0; i < 16; ++i)
            xT[(co + i) * 72 + r] = h[i];
    }
    if (t < 64) {
        const int g = t >> 4, a = t & 15;
        const float* pp = pos + (sA + g) * (NAG * 2);
        const float ax = pp[2 * a], ay = pp[2 * a + 1];
        unsigned m = 0;
        for (int j = 0; j < NAG; ++j) {
            const float dx = ax - pp[2 * j], dy = ay - pp[2 * j + 1];
            if (dx * dx + dy * dy <= R2f && j != a) m |= (1u << j);
        }
        mask[g * 16 + a] = m;
    }
    __syncthreads();

    // ---- agg1 = adj @ x -> xcat cols 64..127 ; wave wv owns ch-tile nt=wv ----
    {
        const int nt = wv;
        const short8 B0 = *(const short8*)&xT[(nt * 16 + ln) * 72 + q * 8];       // rows 0..31
        const short8 B1 = *(const short8*)&xT[(nt * 16 + ln) * 72 + 32 + q * 8];  // rows 32..63
        #pragma unroll
        for (int g = 0; g < 4; ++g) {
            const short8 A = make_adjA(mask[g * 16 + ln], q, g & 1);
            f32x4 acc = {0.f, 0.f, 0.f, 0.f};
            acc = MFMA(A, (g < 2) ? B0 : B1, acc);
            #pragma unroll
            for (int r = 0; r < 4; ++r)
                xcat[(g * 16 + q * 4 + r) * 136 + 64 + nt * 16 + ln] = f2b(acc[r]);
        }
    }
    __syncthreads();

    // ---- GEMM1: x1 = relu(xcat @ [Wroot1;Wrel1] + b1) -> xc2 cols 0..127 + x1T
    {
        const int n0 = 2 * wv, n1 = 2 * wv + 1;
        short8 Bf0[4], Bf1[4];
        #pragma unroll
        for (int s = 0; s < 4; ++s) {
            Bf0[s] = ldfrag(ws, OFF_B1, 8, s, n0, lane);
            Bf1[s] = ldfrag(ws, OFF_B1, 8, s, n1, lane);
        }
        const float b0 = brel1[n0 * 16 + ln], b1 = brel1[n1 * 16 + ln];
        #pragma unroll
        for (int m = 0; m < 4; ++m) {
            short8 Af[4];
            #pragma unroll
            for (int s = 0; s < 4; ++s)
                Af[s] = *(const short8*)&xcat[(m * 16 + ln) * 136 + s * 32 + q * 8];
            f32x4 a0 = {b0, b0, b0, b0}, a1 = {b1, b1, b1, b1};
            #pragma unroll
            for (int s = 0; s < 4; ++s) {
                a0 = MFMA(Af[s], Bf0[s], a0);
                a1 = MFMA(Af[s], Bf1[s], a1);
            }
            #pragma unroll
            for (int r = 0; r < 4; ++r) {
                const int row = m * 16 + q * 4 + r;
                xc2[row * 264 + n0 * 16 + ln] = f2b(fmaxf(a0[r], 0.f));
                xc2[row * 264 + n1 * 16 + ln] = f2b(fmaxf(a1[r], 0.f));
            }
            relu_store4(&x1T[(n0 * 16 + ln) * 72 + m * 16 + q * 4], a0);
            relu_store4(&x1T[(n1 * 16 + ln) * 72 + m * 16 + q * 4], a1);
        }
    }
    __syncthreads();

    // ---- agg2 = adj @ x1 -> xc2 cols 128..255 ; wave owns nt pair ----
    {
        const int n0 = 2 * wv, n1 = 2 * wv + 1;
        short8 B00 = *(const short8*)&x1T[(n0 * 16 + ln) * 72 + q * 8];
        short8 B01 = *(const short8*)&x1T[(n0 * 16 + ln) * 72 + 32 + q * 8];
        short8 B10 = *(const short8*)&x1T[(n1 * 16 + ln) * 72 + q * 8];
        short8 B11 = *(const short8*)&x1T[(n1 * 16 + ln) * 72 + 32 + q * 8];
        #pragma unroll
        for (int g = 0; g < 4; ++g) {
            const short8 A = make_adjA(mask[g * 16 + ln], q, g & 1);
            f32x4 a0 = {0.f, 0.f, 0.f, 0.f}, a1 = a0;
            a0 = MFMA(A, (g < 2) ? B00 : B01, a0);
            a1 = MFMA(A, (g < 2) ? B10 : B11, a1);
            #pragma unroll
            for (int r = 0; r < 4; ++r) {
                const int row = g * 16 + q * 4 + r;
                xc2[row * 264 + 128 + n0 * 16 + ln] = f2b(a0[r]);
                xc2[row * 264 + 128 + n1 * 16 + ln] = f2b(a1[r]);
            }
        }
    }
    __syncthreads();

    // ---- GEMM2: x2 = relu(xc2 @ [Wroot2;Wrel2] + b2) -> x2b (aliases xcat) ----
    {
        const int n0 = 2 * wv, n1 = 2 * wv + 1;
        short8 Bf0[8], Bf1[8];
        #pragma unroll
        for (int s = 0; s < 8; ++s) {
            Bf0[s] = ldfrag(ws, OFF_B2, 8, s, n0, lane);
            Bf1[s] = ldfrag(ws, OFF_B2, 8, s, n1, lane);
        }
        const float b0 = brel2[n0 * 16 + ln], b1 = brel2[n1 * 16 + ln];
        #pragma unroll
        for (int m = 0; m < 4; ++m) {
            short8 Af[8];
            #pragma unroll
            for (int s = 0; s < 8; ++s)
                Af[s] = *(const short8*)&xc2[(m * 16 + ln) * 264 + s * 32 + q * 8];
            f32x4 a0 = {b0, b0, b0, b0}, a1 = {b1, b1, b1, b1};
            f32x4 c0 = {0.f, 0.f, 0.f, 0.f}, c1 = c0;
            #pragma unroll
            for (int s = 0; s < 4; ++s) {
                a0 = MFMA(Af[s], Bf0[s], a0);
                a1 = MFMA(Af[s], Bf1[s], a1);
                c0 = MFMA(Af[s + 4], Bf0[s + 4], c0);
                c1 = MFMA(Af[s + 4], Bf1[s + 4], c1);
            }
            #pragma unroll
            for (int r = 0; r < 4; ++r) {
                const int row = m * 16 + q * 4 + r;
                x2b[row * 136 + n0 * 16 + ln] = f2b(fmaxf(a0[r] + c0[r], 0.f));
                x2b[row * 136 + n1 * 16 + ln] = f2b(fmaxf(a1[r] + c1[r], 0.f));
            }
        }
    }
    __syncthreads();

    // ---- GEMM3: h1 = relu([x1|x2] @ Wh1 + bh1) -> h1b (aliases xT) ----
    {
        const int nt = wv;
        short8 Bf[8];
        #pragma unroll
        for (int s = 0; s < 8; ++s)
            Bf[s] = ldfrag(ws, OFF_H1, 4, s, nt, lane);
        const float b = bh1[nt * 16 + ln];
        #pragma unroll
        for (int m = 0; m < 4; ++m) {
            short8 Af[8];
            #pragma unroll
            for (int s = 0; s < 4; ++s)
                Af[s] = *(const short8*)&xc2[(m * 16 + ln) * 264 + s * 32 + q * 8];       // x1
            #pragma unroll
            for (int s = 0; s < 4; ++s)
                Af[s + 4] = *(const short8*)&x2b[(m * 16 + ln) * 136 + s * 32 + q * 8];   // x2
            f32x4 a = {b, b, b, b}, c = {0.f, 0.f, 0.f, 0.f};
            #pragma unroll
            for (int s = 0; s < 4; ++s) {
                a = MFMA(Af[s], Bf[s], a);
                c = MFMA(Af[s + 4], Bf[s + 4], c);
            }
            #pragma unroll
            for (int r = 0; r < 4; ++r)
                h1b[(m * 16 + q * 4 + r) * 72 + nt * 16 + ln] = f2b(fmaxf(a[r] + c[r], 0.f));
        }
    }
    __syncthreads();

    // ---- GEMM4: h2 = relu(h1 @ Wh2 + bh2) -> h2b (aliases x1T) ----
    {
        const int nt = wv & 1;
        const int m0 = (wv >> 1) * 2;
        short8 Bf[2];
        Bf[0] = ldfrag(ws, OFF_H2, 2, 0, nt, lane);
        Bf[1] = ldfrag(ws, OFF_H2, 2, 1, nt, lane);
        const float b = bh2[nt * 16 + ln];
        #pragma unroll
        for (int mi = 0; mi < 2; ++mi) {
            const int m = m0 + mi;
            const short8 A0 = *(const short8*)&h1b[(m * 16 + ln) * 72 + q * 8];
            const short8 A1 = *(const short8*)&h1b[(m * 16 + ln) * 72 + 32 + q * 8];
            f32x4 a = {b, b, b, b};
            a = MFMA(A0, Bf[0], a);
            a = MFMA(A1, Bf[1], a);
            #pragma unroll
            for (int r = 0; r < 4; ++r)
                h2b[(m * 16 + q * 4 + r) * 40 + nt * 16 + ln] = f2b(fmaxf(a[r], 0.f));
        }
    }
    __syncthreads();

    // ---- GEMM5: out = h2 @ Wh3 + bh3 ; wave wv -> scene wv, f32 stores ----
    {
        const int m = wv;
        const short8 A = *(const short8*)&h2b[(m * 16 + ln) * 40 + q * 8];
        const short8 B = ldfrag(ws, OFF_H3, 1, 0, 0, lane);
        const float b = bh3[ln];
        f32x4 a = {b, b, b, b};
        a = MFMA(A, B, a);
        float* o = out + (sA * 16 + m * 16) * 16;
        #pragma unroll
        for (int r = 0; r < 4; ++r)
            o[(q * 4 + r) * 16 + ln] = a[r];
    }
}

extern "C" void kernel_launch(void* const* d_in, const int* in_sizes, int n_in,
                              void* d_out, int out_size, void* d_ws, size_t ws_size,
                              hipStream_t stream) {
    const float* x      = (const float*)d_in[0];
    const float* pos    = (const float*)d_in[1];
    const float* Wrel1  = (const float*)d_in[2];
    const float* brel1  = (const float*)d_in[3];
    const float* Wroot1 = (const float*)d_in[4];
    const float* Wrel2  = (const float*)d_in[5];
    const float* brel2  = (const float*)d_in[6];
    const float* Wroot2 = (const float*)d_in[7];
    const float* Wh1    = (const float*)d_in[8];
    const float* bh1    = (const float*)d_in[9];
    const float* Wh2    = (const float*)d_in[10];
    const float* bh2    = (const float*)d_in[11];
    const float* Wh3    = (const float*)d_in[12];
    const float* bh3    = (const float*)d_in[13];
    u16* ws = (u16*)d_ws;

    swizzle_w<<<(SWZ_UNITS + 255) / 256, 256, 0, stream>>>(
        Wrel1, Wroot1, Wrel2, Wroot2, Wh1, Wh2, Wh3, ws);
    gnn_fused4<<<NBLK, 256, 0, stream>>>(
        x, pos, brel1, brel2, bh1, bh2, bh3, ws, (float*)d_out);
}

// Round 9
// 125.019 us; speedup vs baseline: 1.3311x; 1.0844x over previous
//
#include <hip/hip_runtime.h>

#define NAG 16
#define SPB 4        // scenes per block, one M=64 batch, single pass
#define NBLK 2048
#define R2f 64.0f

typedef unsigned short u16;
typedef __attribute__((ext_vector_type(8))) short short8;
typedef __attribute__((ext_vector_type(4))) float f32x4;

#define MFMA(a, b, c) __builtin_amdgcn_mfma_f32_16x16x32_bf16(a, b, c, 0, 0, 0)

// ws blob offsets in u16 units (R3-proven layout)
#define OFF_B1 0        // [Wroot1;Wrel1]  K=128 N=128  S=4 T=8  (root s0..1, rel s2..3)
#define OFF_B2 16384    // [Wroot2;Wrel2]  K=256 N=128  S=8 T=8  (root s0..3, rel s4..7)
#define OFF_H1 49152    // Wh1             K=256 N=64   S=8 T=4
#define OFF_H2 65536    // Wh2             K=64  N=32   S=2 T=2
#define OFF_H3 67584    // Wh3             K=32  N=16   S=1 T=1
#define SWZ_UNITS 8512

__device__ __forceinline__ u16 f2b(float f) {            // RNE (swizzle only)
    unsigned u = __float_as_uint(f);
    unsigned r = u + 0x7FFFu + ((u >> 16) & 1u);
    return (u16)(r >> 16);
}
// fast round-to-nearest (ties up) — hot-kernel path; sub-ulp delta vs RNE
__device__ __forceinline__ unsigned rb(float f) {
    return (__float_as_uint(f) + 0x8000u) >> 16;
}
__device__ __forceinline__ unsigned pk2(float a, float b) {
    return ((__float_as_uint(a) + 0x8000u) >> 16) |
           ((__float_as_uint(b) + 0x8000u) & 0xFFFF0000u);
}

// ---------------- weight pre-swizzle: W[K][N] f32 -> fragment order bf16 -----
__global__ __launch_bounds__(256) void swizzle_w(
    const float* __restrict__ Wrel1, const float* __restrict__ Wroot1,
    const float* __restrict__ Wrel2, const float* __restrict__ Wroot2,
    const float* __restrict__ Wh1,  const float* __restrict__ Wh2,
    const float* __restrict__ Wh3,  u16* __restrict__ ws)
{
    const int u = blockIdx.x * 256 + threadIdx.x;
    if (u >= SWZ_UNITS) return;
    int v, T, N, ksplit;
    const float *W, *W2;
    u16* dst;
    if (u < 2048)      { v = u;        T = 8; N = 128; ksplit = 64;  W = Wroot1; W2 = Wrel1; dst = ws + OFF_B1 + v * 8; }
    else if (u < 6144) { v = u - 2048; T = 8; N = 128; ksplit = 128; W = Wroot2; W2 = Wrel2; dst = ws + OFF_B2 + v * 8; }
    else if (u < 8192) { v = u - 6144; T = 4; N = 64;  ksplit = 1 << 30; W = Wh1; W2 = Wh1; dst = ws + OFF_H1 + v * 8; }
    else if (u < 8448) { v = u - 8192; T = 2; N = 32;  ksplit = 1 << 30; W = Wh2; W2 = Wh2; dst = ws + OFF_H2 + v * 8; }
    else               { v = u - 8448; T = 1; N = 16;  ksplit = 1 << 30; W = Wh3; W2 = Wh3; dst = ws + OFF_H3 + v * 8; }
    const int lane = v & 63;
    const int t = (v >> 6) % T;
    const int s = (v >> 6) / T;
    const int n = t * 16 + (lane & 15);
    const int k0 = s * 32 + (lane >> 4) * 8;
    #pragma unroll
    for (int j = 0; j < 8; ++j) {
        const int k = k0 + j;
        const float val = (k < ksplit) ? W[k * N + n] : W2[(k - ksplit) * N + n];
        dst[j] = f2b(val);
    }
}

__device__ __forceinline__ short8 ldfrag(const u16* __restrict__ ws, int off,
                                         int T, int s, int tile, int lane) {
    return *(const short8*)(ws + off + (size_t)(((s * T + tile) * 64 + lane) * 8));
}

// adjacency A-fragment, scene g packed in 32-row K window (2 scenes):
// A[m=lane&15][k=q*8+j]; valid only in this scene's half (q>>1 == odd).
__device__ __forceinline__ short8 make_adjA(unsigned m, int q, int odd) {
    union { short8 v; unsigned u[4]; } r;
    const bool on = (q >> 1) == odd;
    const int base = (q & 1) * 8;
    #pragma unroll
    for (int jj = 0; jj < 4; ++jj) {
        const int k0 = base + 2 * jj;
        const unsigned lo = (on && ((m >> k0) & 1u)) ? 0x3F80u : 0u;
        const unsigned hi = (on && ((m >> (k0 + 1)) & 1u)) ? 0x3F80u : 0u;
        r.u[jj] = lo | (hi << 16);
    }
    return r.v;
}

// LDS (u16 units): xb [64][136] (x cols0..63; later x2 cols0..127)   0..8704
//                  yT [128][72] (y^T ch-major; later h1 [64][72])    8704..17920
//                  x1b [64][136] (x1; later h2 [64][40])             17920..26624
// 53 KB total -> 3 blocks/CU. Barriers: S0|L1|L2|GEMM3|GEMM45 = 4.
// Key identity (R4-proven): adj@(x@Wrel) == (adj@x)@Wrel, making each
// GraphConv layer wave-local after one y round-trip through LDS.
__global__ __launch_bounds__(256) void gnn_fused5(
    const float* __restrict__ x, const float* __restrict__ pos,
    const float* __restrict__ brel1, const float* __restrict__ brel2,
    const float* __restrict__ bh1,  const float* __restrict__ bh2,
    const float* __restrict__ bh3,
    const u16* __restrict__ ws, float* __restrict__ out)
{
    __shared__ __align__(16) u16 pool[26624];
    __shared__ unsigned mask[64];
    u16* const xb  = pool;          // also x2
    u16* const yT  = pool + 8704;   // also h1
    u16* const x1b = pool + 17920;  // also h2

    const int t = threadIdx.x;
    const int wv = t >> 6, lane = t & 63, ln = lane & 15, q = lane >> 4;
    const int c0 = 32 * wv;                 // wave's output-col base (L1/L2)
    const int n0 = 2 * wv, n1 = 2 * wv + 1;
    const size_t sA = (size_t)blockIdx.x * SPB;

    // ---- S0: stage x (f32->bf16) + adjacency masks ----
    {
        const int r = t >> 2, co = (t & 3) * 16;
        const float* src = x + (sA * 16 + r) * 64 + co;
        const float4 v0 = *(const float4*)(src);
        const float4 v1 = *(const float4*)(src + 4);
        const float4 v2 = *(const float4*)(src + 8);
        const float4 v3 = *(const float4*)(src + 12);
        uint4 ua, ub;
        ua.x = pk2(v0.x, v0.y); ua.y = pk2(v0.z, v0.w);
        ua.z = pk2(v1.x, v1.y); ua.w = pk2(v1.z, v1.w);
        ub.x = pk2(v2.x, v2.y); ub.y = pk2(v2.z, v2.w);
        ub.z = pk2(v3.x, v3.y); ub.w = pk2(v3.z, v3.w);
        *(uint4*)&xb[r * 136 + co]     = ua;
        *(uint4*)&xb[r * 136 + co + 8] = ub;
    }
    if (t < 64) {
        const int g = t >> 4, a = t & 15;
        const float* pp = pos + (sA + g) * (NAG * 2);
        const float ax = pp[2 * a], ay = pp[2 * a + 1];
        unsigned m = 0;
        for (int j = 0; j < NAG; ++j) {
            const float dx = ax - pp[2 * j], dy = ay - pp[2 * j + 1];
            if (dx * dx + dy * dy <= R2f && j != a) m |= (1u << j);
        }
        mask[g * 16 + a] = m;
    }
    __syncthreads();

    short8 adjA[4];
    #pragma unroll
    for (int g = 0; g < 4; ++g) adjA[g] = make_adjA(mask[g * 16 + ln], q, g & 1);

    // ---- L1: x1 = relu(adj@(x@Wrel1) + x@Wroot1 + b1) -> x1b ----
    {
        short8 Brl[2][2], Bro[2][2], Af[4][2];
        #pragma unroll
        for (int s = 0; s < 2; ++s) {
            Brl[s][0] = ldfrag(ws, OFF_B1, 8, s + 2, n0, lane);
            Brl[s][1] = ldfrag(ws, OFF_B1, 8, s + 2, n1, lane);
        }
        #pragma unroll
        for (int m = 0; m < 4; ++m) {               // y1 -> yT (no relu, no bias)
            Af[m][0] = *(const short8*)&xb[(m * 16 + ln) * 136 + q * 8];
            Af[m][1] = *(const short8*)&xb[(m * 16 + ln) * 136 + 32 + q * 8];
            f32x4 a0 = {0.f, 0.f, 0.f, 0.f}, a1 = a0;
            a0 = MFMA(Af[m][0], Brl[0][0], a0); a0 = MFMA(Af[m][1], Brl[1][0], a0);
            a1 = MFMA(Af[m][0], Brl[0][1], a1); a1 = MFMA(Af[m][1], Brl[1][1], a1);
            uint2 u0; u0.x = pk2(a0[0], a0[1]); u0.y = pk2(a0[2], a0[3]);
            uint2 u1; u1.x = pk2(a1[0], a1[1]); u1.y = pk2(a1[2], a1[3]);
            *(uint2*)&yT[(c0 + ln) * 72 + m * 16 + q * 4]      = u0;
            *(uint2*)&yT[(c0 + 16 + ln) * 72 + m * 16 + q * 4] = u1;
        }
        short8 By[2][2];
        #pragma unroll
        for (int w = 0; w < 2; ++w) {               // wave-local readback
            By[w][0] = *(const short8*)&yT[(c0 + ln) * 72 + w * 32 + q * 8];
            By[w][1] = *(const short8*)&yT[(c0 + 16 + ln) * 72 + w * 32 + q * 8];
        }
        #pragma unroll
        for (int s = 0; s < 2; ++s) {
            Bro[s][0] = ldfrag(ws, OFF_B1, 8, s, n0, lane);
            Bro[s][1] = ldfrag(ws, OFF_B1, 8, s, n1, lane);
        }
        const float b0 = brel1[c0 + ln], b1 = brel1[c0 + 16 + ln];
        #pragma unroll
        for (int g = 0; g < 4; ++g) {
            f32x4 a0 = {b0, b0, b0, b0}, a1 = {b1, b1, b1, b1};
            a0 = MFMA(Af[g][0], Bro[0][0], a0); a0 = MFMA(Af[g][1], Bro[1][0], a0);
            a1 = MFMA(Af[g][0], Bro[0][1], a1); a1 = MFMA(Af[g][1], Bro[1][1], a1);
            a0 = MFMA(adjA[g], By[g >> 1][0], a0);
            a1 = MFMA(adjA[g], By[g >> 1][1], a1);
            #pragma unroll
            for (int r = 0; r < 4; ++r) {
                const int row = g * 16 + q * 4 + r;
                x1b[row * 136 + c0 + ln]      = (u16)rb(fmaxf(a0[r], 0.f));
                x1b[row * 136 + c0 + 16 + ln] = (u16)rb(fmaxf(a1[r], 0.f));
            }
        }
    }
    __syncthreads();

    // ---- L2: x2 = relu(adj@(x1@Wrel2) + x1@Wroot2 + b2) -> xb (x dead) ----
    {
        short8 Brl[4][2];
        #pragma unroll
        for (int s = 0; s < 4; ++s) {
            Brl[s][0] = ldfrag(ws, OFF_B2, 8, s + 4, n0, lane);
            Brl[s][1] = ldfrag(ws, OFF_B2, 8, s + 4, n1, lane);
        }
        #pragma unroll
        for (int m = 0; m < 4; ++m) {               // y2 -> yT
            f32x4 a0 = {0.f, 0.f, 0.f, 0.f}, a1 = a0;
            #pragma unroll
            for (int s = 0; s < 4; ++s) {
                const short8 A = *(const short8*)&x1b[(m * 16 + ln) * 136 + s * 32 + q * 8];
                a0 = MFMA(A, Brl[s][0], a0);
                a1 = MFMA(A, Brl[s][1], a1);
            }
            uint2 u0; u0.x = pk2(a0[0], a0[1]); u0.y = pk2(a0[2], a0[3]);
            uint2 u1; u1.x = pk2(a1[0], a1[1]); u1.y = pk2(a1[2], a1[3]);
            *(uint2*)&yT[(c0 + ln) * 72 + m * 16 + q * 4]      = u0;
            *(uint2*)&yT[(c0 + 16 + ln) * 72 + m * 16 + q * 4] = u1;
        }
        short8 By[2][2];
        #pragma unroll
        for (int w = 0; w < 2; ++w) {
            By[w][0] = *(const short8*)&yT[(c0 + ln) * 72 + w * 32 + q * 8];
            By[w][1] = *(const short8*)&yT[(c0 + 16 + ln) * 72 + w * 32 + q * 8];
        }
        short8 Bro[4][2];
        #pragma unroll
        for (int s = 0; s < 4; ++s) {
            Bro[s][0] = ldfrag(ws, OFF_B2, 8, s, n0, lane);
            Bro[s][1] = ldfrag(ws, OFF_B2, 8, s, n1, lane);
        }
        const float b0 = brel2[c0 + ln], b1 = brel2[c0 + 16 + ln];
        #pragma unroll
        for (int g = 0; g < 4; ++g) {
            f32x4 a0 = {b0, b0, b0, b0}, a1 = {b1, b1, b1, b1};
            #pragma unroll
            for (int s = 0; s < 4; ++s) {
                const short8 A = *(const short8*)&x1b[(g * 16 + ln) * 136 + s * 32 + q * 8];
                a0 = MFMA(A, Bro[s][0], a0);
                a1 = MFMA(A, Bro[s][1], a1);
            }
            a0 = MFMA(adjA[g], By[g >> 1][0], a0);
            a1 = MFMA(adjA[g], By[g >> 1][1], a1);
            #pragma unroll
            for (int r = 0; r < 4; ++r) {
                const int row = g * 16 + q * 4 + r;
                xb[row * 136 + c0 + ln]      = (u16)rb(fmaxf(a0[r], 0.f));
                xb[row * 136 + c0 + 16 + ln] = (u16)rb(fmaxf(a1[r], 0.f));
            }
        }
    }
    __syncthreads();

    // ---- GEMM3: h1 = relu([x1|x2] @ Wh1 + bh1), n-tile = wv -> yT region ----
    {
        short8 Bf[8];
        #pragma unroll
        for (int s = 0; s < 8; ++s) Bf[s] = ldfrag(ws, OFF_H1, 4, s, wv, lane);
        const float b = bh1[wv * 16 + ln];
        #pragma unroll
        for (int m = 0; m < 4; ++m) {
            f32x4 a = {b, b, b, b}, c = {0.f, 0.f, 0.f, 0.f};
            #pragma unroll
            for (int s = 0; s < 4; ++s) {
                const short8 A1 = *(const short8*)&x1b[(m * 16 + ln) * 136 + s * 32 + q * 8];
                const short8 A2 = *(const short8*)&xb[(m * 16 + ln) * 136 + s * 32 + q * 8];
                a = MFMA(A1, Bf[s], a);
                c = MFMA(A2, Bf[s + 4], c);
            }
            #pragma unroll
            for (int r = 0; r < 4; ++r)
                yT[(m * 16 + q * 4 + r) * 72 + wv * 16 + ln] = (u16)rb(fmaxf(a[r] + c[r], 0.f));
        }
    }
    __syncthreads();

    // ---- GEMM4+5 (wave-local: wave wv = scene wv): h2 then out ----
    {
        const u16* h1b = yT;
        u16* h2b = x1b;                              // x1 dead
        const short8 A0 = *(const short8*)&h1b[(wv * 16 + ln) * 72 + q * 8];
        const short8 A1 = *(const short8*)&h1b[(wv * 16 + ln) * 72 + 32 + q * 8];
        #pragma unroll
        for (int nt = 0; nt < 2; ++nt) {
            const short8 B0 = ldfrag(ws, OFF_H2, 2, 0, nt, lane);
            const short8 B1 = ldfrag(ws, OFF_H2, 2, 1, nt, lane);
            const float b = bh2[nt * 16 + ln];
            f32x4 a = {b, b, b, b};
            a = MFMA(A0, B0, a);
            a = MFMA(A1, B1, a);
            #pragma unroll
            for (int r = 0; r < 4; ++r)
                h2b[(wv * 16 + q * 4 + r) * 40 + nt * 16 + ln] = (u16)rb(fmaxf(a[r], 0.f));
        }
        const short8 A = *(const short8*)&h2b[(wv * 16 + ln) * 40 + q * 8];
        const short8 B = ldfrag(ws, OFF_H3, 1, 0, 0, lane);
        const float b = bh3[ln];
        f32x4 a = {b, b, b, b};
        a = MFMA(A, B, a);
        #pragma unroll
        for (int r = 0; r < 4; ++r)
            out[(sA * 16 + wv * 16 + q * 4 + r) * 16 + ln] = a[r];
    }
}

extern "C" void kernel_launch(void* const* d_in, const int* in_sizes, int n_in,
                              void* d_out, int out_size, void* d_ws, size_t ws_size,
                              hipStream_t stream) {
    const float* x      = (const float*)d_in[0];
    const float* pos    = (const float*)d_in[1];
    const float* Wrel1  = (const float*)d_in[2];
    const float* brel1  = (const float*)d_in[3];
    const float* Wroot1 = (const float*)d_in[4];
    const float* Wrel2  = (const float*)d_in[5];
    const float* brel2  = (const float*)d_in[6];
    const float* Wroot2 = (const float*)d_in[7];
    const float* Wh1    = (const float*)d_in[8];
    const float* bh1    = (const float*)d_in[9];
    const float* Wh2    = (const float*)d_in[10];
    const float* bh2    = (const float*)d_in[11];
    const float* Wh3    = (const float*)d_in[12];
    const float* bh3    = (const float*)d_in[13];
    u16* ws = (u16*)d_ws;

    swizzle_w<<<(SWZ_UNITS + 255) / 256, 256, 0, stream>>>(
        Wrel1, Wroot1, Wrel2, Wroot2, Wh1, Wh2, Wh3, ws);
    gnn_fused5<<<NBLK, 256, 0, stream>>>(
        x, pos, brel1, brel2, bh1, bh2, bh3, ws, (float*)d_out);
}